// Round 6
// baseline (3123.752 us; speedup 1.0000x reference)
//
#include <hip/hip_runtime.h>
#include <hip/hip_bf16.h>

// HINGE_56985626083396 — fused embedding-conv-BN-min-FC forward on MI355X.
//
// Round-15: full-N blocks + T14 prefetch on the two-crossing structure.
// r14 counters (527us/pass): FETCH 125MB at only 237 GB/s, all pipes idle ->
// (a) 2 n-sibling blocks double gather demand (368MB vs 51.2MB unique) so
// L3 re-touch hit rate collapses; (b) serial chunk loop exposes the full
// scatter round-trip every chunk (no overlap). Fixes:
//   - block = 32 batches x FULL N=512: 1024 thr, 16 waves (2m x 8n), wave
//     tile 64x64, acc[4][4] (64 VGPR, spill-safe). Demand halves to 184MB.
//     LDS 126.5KB -> 1 block/CU, 4 waves/SIMD.
//   - flat 28-chunk schedule per pass: G1 (8, K=512, 64 rows mirrored x2)
//     -> H (12, K=768, REPLICATED A rows: acc[r] all get H[b,f]) -> T (8,
//     K=512 [kr|kv]: acc[r] += t_r). Window 2+r complete in acc reg r,
//     no Hbuf/min1 buffers (r14 algebra, verified).
//   - T14 issue-early/write-late: chunk ch+1's A+B global loads issued
//     BEFORE mma(ch), LDS-written after the post-mma barrier. Gather
//     latency hides under MFMA+barrier instead of serializing.
// stats pass: G1 epilogue (windows 0,1) + T epilogue (2..5) -> LDS red ->
// one accum flush. final pass: G1 -> m1 bf16 in LDS (32KB); T -> m2 =
// min_r relu(a_r*acc_r+c_r), min(m1), dot fcw, shfl-reduce -> outacc.
// bf16 tables (51.2MB) cvt'd once into workspace. conv biases skipped
// (BN mean-subtraction cancels them exactly).

typedef __hip_bfloat16 bf16;
typedef short bf16x8 __attribute__((ext_vector_type(8)));   // 8 bf16 in 4 VGPRs
typedef float f32x4 __attribute__((ext_vector_type(4)));

#define BATCH 32768

__device__ __forceinline__ unsigned short f2b(float f) {
    union { float f; unsigned u; } v; v.f = f;
    unsigned r = v.u + 0x7fffu + ((v.u >> 16) & 1u);   // round-to-nearest-even
    return (unsigned short)(r >> 16);
}

__device__ __forceinline__ float b2f(unsigned short u) {
    union { unsigned x; float f; } v; v.x = ((unsigned)u) << 16;
    return v.f;
}

__global__ __launch_bounds__(256)
void cvt_kernel(const float* __restrict__ src, unsigned short* __restrict__ dst, int n4)
{
    int i = blockIdx.x * 256 + threadIdx.x;
    if (i >= n4) return;
    float4 v = ((const float4*)src)[i];
    ushort4 h;
    h.x = f2b(v.x); h.y = f2b(v.y); h.z = f2b(v.z); h.w = f2b(v.w);
    ((ushort4*)dst)[i] = h;
}

// One block: 32 batches x 512 f. 1024 threads, 16 waves (2m x 8n).
// A tile 128 rows x 64 k; per chunk each thread loads 1 uint4 of A, 4 of B.
template<bool FINAL>
__global__ __launch_bounds__(1024, 4)
void pass_kernel(const int* __restrict__ x, const bf16* __restrict__ embR,
                 const bf16* __restrict__ embV, const bf16* __restrict__ W1b,
                 const bf16* __restrict__ W2b, float* __restrict__ accum,
                 const float* __restrict__ coef, const float* __restrict__ fcw,
                 float* __restrict__ outacc)
{
    __shared__ __align__(16) short Ash[128 * 72];   // +8 pad per row
    __shared__ __align__(16) short Bsh[512 * 72];
    __shared__ int xsh[384];
    __shared__ __align__(16) float scr[8192];       // red (stats) / m1s (final)

    const int tid = threadIdx.x;
    const int b0  = blockIdx.x * 32;

    for (int i = tid; i < 384; i += 1024) xsh[i] = x[b0 * 12 + i];
    if constexpr (!FINAL)
        for (int i = tid; i < 6144; i += 1024) scr[i] = 0.f;
    __syncthreads();

    const int lane = tid & 63;
    const int wv   = tid >> 6;                      // 0..15
    const int wmb  = (wv >> 3) * 64;                // m-half (0/64)
    const int wnb  = (wv & 7) * 64;                 // n-block (0..448)
    const int quad = lane >> 4;
    const int l16  = lane & 15;
    const int arow = tid >> 3;                      // staging row 0..127
    const int aoff = tid & 7;                       // uint4 within 128B slice

    // ---- flat 28-step schedule: G1 st 0..7, H st 8..19, T st 20..27 ----
    auto issue = [&](int st, uint4& a, uint4 (&b)[4]) {
        int idx; const bf16* tab;
        if (st < 8) {                               // G1: [fv_kk | fr0]
            int seg = st >> 2;
            int vr = arow & 63, bl = vr >> 1, kk = vr & 1;
            if (seg == 0) { idx = xsh[bl * 12 + 2 * kk + 1]; tab = embV; }
            else          { idx = xsh[bl * 12];              tab = embR; }
            a = *((const uint4*)(tab + (size_t)idx * 256 + (st & 3) * 64) + aoff);
            #pragma unroll
            for (int it = 0; it < 4; ++it) {
                int flat = tid + it * 1024, fr = flat >> 3, o8 = flat & 7;
                b[it] = *((const uint4*)(W1b + (size_t)fr * 512 + st * 64) + o8);
            }
        } else if (st < 20) {                       // H: replicated hrt rows
            int ch = st - 8, seg = ch >> 2;
            int bl = arow >> 2;
            if (seg == 0)      { idx = xsh[bl * 12 + 1]; tab = embV; }
            else if (seg == 1) { idx = xsh[bl * 12 + 0]; tab = embR; }
            else               { idx = xsh[bl * 12 + 3]; tab = embV; }
            a = *((const uint4*)(tab + (size_t)idx * 256 + (ch & 3) * 64) + aoff);
            #pragma unroll
            for (int it = 0; it < 4; ++it) {
                int flat = tid + it * 1024, fr = flat >> 3, o8 = flat & 7;
                b[it] = *((const uint4*)(W2b + (size_t)fr * 1280 + ch * 64) + o8);
            }
        } else {                                    // T: [kr_kk | kv_kk]
            int ch = st - 20, seg = ch >> 2;
            int bl = arow >> 2, kk = arow & 3;
            if (seg == 0) { idx = xsh[bl * 12 + 2 * kk + 4]; tab = embR; }
            else          { idx = xsh[bl * 12 + 2 * kk + 5]; tab = embV; }
            a = *((const uint4*)(tab + (size_t)idx * 256 + (ch & 3) * 64) + aoff);
            #pragma unroll
            for (int it = 0; it < 4; ++it) {
                int flat = tid + it * 1024, fr = flat >> 3, o8 = flat & 7;
                b[it] = *((const uint4*)(W2b + (size_t)fr * 1280 + 768 + ch * 64) + o8);
            }
        }
    };
    auto wA = [&](const uint4& a) {
        *(uint4*)&Ash[arow * 72 + aoff * 8] = a;
    };
    auto wB = [&](const uint4 (&b)[4]) {
        #pragma unroll
        for (int it = 0; it < 4; ++it) {
            int flat = tid + it * 1024, fr = flat >> 3, o8 = flat & 7;
            *(uint4*)&Bsh[fr * 72 + o8 * 8] = b[it];
        }
    };

    f32x4 acc[4][4];
    #pragma unroll
    for (int i = 0; i < 4; ++i)
        #pragma unroll
        for (int j = 0; j < 4; ++j)
            acc[i][j] = (f32x4){0.f, 0.f, 0.f, 0.f};

    uint4 pa, pb[4];
    issue(0, pa, pb);

    #pragma unroll 1
    for (int st = 0; st < 28; ++st) {
        wA(pa); wB(pb);                             // waits on in-flight loads
        uint4 na, nb[4];
        if (st < 27) issue(st + 1, na, nb);         // issue-early (in flight)
        __syncthreads();
        // ---- mma ----
        #pragma unroll
        for (int ks = 0; ks < 64; ks += 32) {
            bf16x8 af[4], bf_[4];
            #pragma unroll
            for (int t = 0; t < 4; ++t)
                af[t]  = *(const bf16x8*)&Ash[(wmb + t * 16 + l16) * 72 + ks + quad * 8];
            #pragma unroll
            for (int t = 0; t < 4; ++t)
                bf_[t] = *(const bf16x8*)&Bsh[(wnb + t * 16 + l16) * 72 + ks + quad * 8];
            #pragma unroll
            for (int i = 0; i < 4; ++i)
                #pragma unroll
                for (int j = 0; j < 4; ++j)
                    acc[i][j] = __builtin_amdgcn_mfma_f32_16x16x32_bf16(
                        af[i], bf_[j], acc[i][j], 0, 0, 0);
        }
        // ---- G1 epilogue at st==7 (windows 0,1), then reset acc ----
        if (st == 7) {
            if (wv < 8) {                           // real rows (wmb==0)
                if constexpr (!FINAL) {
                    #pragma unroll
                    for (int j = 0; j < 4; ++j) {
                        int fl = wnb + j * 16 + l16;
                        #pragma unroll
                        for (int r = 0; r < 4; ++r) {
                            float sr = 0.f, qr = 0.f;
                            #pragma unroll
                            for (int i = 0; i < 4; ++i) {
                                float v = acc[i][j][r];
                                sr += v; qr += v * v;
                            }
                            atomicAdd(&scr[(r & 1) * 512 + fl], sr);
                            atomicAdd(&scr[3072 + (r & 1) * 512 + fl], qr);
                        }
                    }
                } else {
                    unsigned short* m1s = (unsigned short*)scr;
                    #pragma unroll
                    for (int j = 0; j < 4; ++j) {
                        int fl = wnb + j * 16 + l16;
                        float a0 = coef[fl],       c0 = coef[3072 + fl];
                        float a1 = coef[512 + fl], c1 = coef[3584 + fl];
                        #pragma unroll
                        for (int i = 0; i < 4; ++i)
                            #pragma unroll
                            for (int rp = 0; rp < 2; ++rp) {
                                int bl = i * 8 + quad * 2 + rp;
                                float v0 = fmaxf(a0 * acc[i][j][rp * 2]     + c0, 0.f);
                                float v1 = fmaxf(a1 * acc[i][j][rp * 2 + 1] + c1, 0.f);
                                m1s[bl * 512 + fl] = f2b(fminf(v0, v1));
                            }
                    }
                }
            }
            #pragma unroll
            for (int i = 0; i < 4; ++i)
                #pragma unroll
                for (int j = 0; j < 4; ++j)
                    acc[i][j] = (f32x4){0.f, 0.f, 0.f, 0.f};
        }
        __syncthreads();
        if (st < 27) {
            pa = na;
            #pragma unroll
            for (int it = 0; it < 4; ++it) pb[it] = nb[it];
        }
    }

    // ---- T epilogue: acc reg r == window 2+r (H folded in) ----
    if constexpr (!FINAL) {
        #pragma unroll
        for (int j = 0; j < 4; ++j) {
            int fl = wnb + j * 16 + l16;
            #pragma unroll
            for (int r = 0; r < 4; ++r) {
                float sr = 0.f, qr = 0.f;
                #pragma unroll
                for (int i = 0; i < 4; ++i) {
                    float v = acc[i][j][r];
                    sr += v; qr += v * v;
                }
                atomicAdd(&scr[(2 + r) * 512 + fl], sr);
                atomicAdd(&scr[3072 + (2 + r) * 512 + fl], qr);
            }
        }
        __syncthreads();
        for (int i2 = tid; i2 < 3072; i2 += 1024) {
            atomicAdd(&accum[i2], scr[i2]);
            atomicAdd(&accum[3072 + i2], scr[3072 + i2]);
        }
    } else {
        const unsigned short* m1s = (const unsigned short*)scr;
        float dp[4] = {0.f, 0.f, 0.f, 0.f};
        #pragma unroll
        for (int j = 0; j < 4; ++j) {
            int f = wnb + j * 16 + l16;
            float a[4], c[4];
            #pragma unroll
            for (int r = 0; r < 4; ++r) {
                a[r] = coef[(2 + r) * 512 + f];
                c[r] = coef[3072 + (2 + r) * 512 + f];
            }
            float fw = fcw[f];
            #pragma unroll
            for (int i = 0; i < 4; ++i) {
                int bb = 16 * (wv >> 3) + i * 4 + quad;
                float mv = 1e30f;
                #pragma unroll
                for (int r = 0; r < 4; ++r)
                    mv = fminf(mv, fmaxf(a[r] * acc[i][j][r] + c[r], 0.f));
                mv = fminf(mv, b2f(m1s[bb * 512 + f]));
                dp[i] += mv * fw;
            }
        }
        #pragma unroll
        for (int i = 0; i < 4; ++i) {
            float v = dp[i];
            v += __shfl_xor(v, 1); v += __shfl_xor(v, 2);
            v += __shfl_xor(v, 4); v += __shfl_xor(v, 8);
            if (l16 == 0)
                atomicAdd(&outacc[b0 + 16 * (wv >> 3) + i * 4 + quad], v);
        }
    }
}

__global__ void bncoef_kernel(const float* __restrict__ accum,
                              const float* __restrict__ g1, const float* __restrict__ be1,
                              const float* __restrict__ g2, const float* __restrict__ be2,
                              float* __restrict__ coef)
{
    int id = blockIdx.x * 256 + threadIdx.x;
    if (id >= 3072) return;
    int kw = id >> 9, f = id & 511;
    float mean = accum[id] * (1.f / BATCH);
    float var  = accum[3072 + id] * (1.f / BATCH) - mean * mean;
    float g  = kw < 2 ? g1[f] : g2[f];
    float be = kw < 2 ? be1[f] : be2[f];
    float a  = g * rsqrtf(var + 1e-5f);
    coef[id] = a;
    coef[3072 + id] = be - a * mean;
}

__global__ void finish_kernel(const float* __restrict__ outacc,
                              const float* __restrict__ fcb, float* __restrict__ out)
{
    int b = blockIdx.x * 256 + threadIdx.x;
    if (b < BATCH)
        out[b] = outacc[b] + fcb[0];
}

extern "C" void kernel_launch(void* const* d_in, const int* in_sizes, int n_in,
                              void* d_out, int out_size, void* d_ws, size_t ws_size,
                              hipStream_t stream)
{
    (void)in_sizes; (void)n_in; (void)out_size; (void)ws_size;
    const int*   x    = (const int*)  d_in[0];
    const float* embR = (const float*)d_in[2];    // 50000 x 256 f32
    const float* embV = (const float*)d_in[3];    // 50000 x 256 f32
    const float* W1   = (const float*)d_in[4];    // 512 x 2 x 256 f32
    const float* g1   = (const float*)d_in[6];
    const float* be1  = (const float*)d_in[7];
    const float* W2   = (const float*)d_in[8];    // 512 x 5 x 256 f32
    const float* g2   = (const float*)d_in[10];
    const float* be2  = (const float*)d_in[11];
    const float* fcw  = (const float*)d_in[12];   // 512 f32
    const float* fcb  = (const float*)d_in[13];

    char* wsb = (char*)d_ws;
    float* accum  = (float*)wsb;                          //        0: 24 KB
    float* coef   = accum + 6144;                         //    24576: 24 KB
    float* outacc = coef + 6144;                          //    49152: 128 KB
    bf16*  Wbf1   = (bf16*)(wsb + 180224);                //   512 KB
    bf16*  Wbf2   = (bf16*)(wsb + 704512);                //  1.25 MB
    bf16*  embRb  = (bf16*)(wsb + 2015232);               //  25.6 MB
    bf16*  embVb  = (bf16*)(wsb + 27615232);              //  -> 53215232 (53.2MB)

    hipMemsetAsync(accum, 0, 6144 * sizeof(float), stream);
    hipMemsetAsync(outacc, 0, BATCH * sizeof(float), stream);
    cvt_kernel<<<256, 256, 0, stream>>>(W1, (unsigned short*)Wbf1, 65536);
    cvt_kernel<<<640, 256, 0, stream>>>(W2, (unsigned short*)Wbf2, 163840);
    cvt_kernel<<<12500, 256, 0, stream>>>(embR, (unsigned short*)embRb, 3200000);
    cvt_kernel<<<12500, 256, 0, stream>>>(embV, (unsigned short*)embVb, 3200000);

    pass_kernel<false><<<1024, 1024, 0, stream>>>(
        x, embRb, embVb, Wbf1, Wbf2, accum, nullptr, nullptr, nullptr);
    bncoef_kernel<<<12, 256, 0, stream>>>(accum, g1, be1, g2, be2, coef);
    pass_kernel<true><<<1024, 1024, 0, stream>>>(
        x, embRb, embVb, Wbf1, Wbf2, nullptr, coef, fcw, outacc);
    finish_kernel<<<128, 256, 0, stream>>>(outacc, fcb, (float*)d_out);
}

// Round 8
// 1029.851 us; speedup vs baseline: 3.0332x; 3.0332x over previous
//
#include <hip/hip_runtime.h>
#include <hip/hip_bf16.h>

// HINGE_56985626083396 — fused embedding-conv-BN-min-FC forward on MI355X.
//
// Round-17: r16 (A-dbuf + B-from-L2 on the r10 structure) with the stats
// zero-init bug fixed. r16 failed absmax 0.27 because MODE_STATS zeroed only
// RPB*128 floats of `red` while the reduction uses RPB*512 (sums+squares,
// 256-wide tile) -> garbage BN stats. r10's original had RPB*512.
//
// Mechanics under test (unchanged from r16):
//   (a) A double-buffered in LDS: chunk ch+1's scattered gather issued
//       BEFORE the barrier, written to the alternate buffer next iter ->
//       misses stay in flight across MFMA instead of draining at every
//       barrier (the 400 GB/s concurrency theory of r10's idle-pipes
//       profile).
//   (b) B read directly from global in the MFMA loop (W1b/W2b 0.5-1.25MB,
//       L2-resident): Bsh and its barrier gone; one barrier per chunk.
// Register audit: acc 64 + prefetch 16 + addressing ~30 = ~110 < 128 cap
// (launch_bounds(512,4)); LDS 74KB -> 2 blocks/CU.
//
// Structure (unchanged from r10):
//   H[b,f]   = hrt . W2[:,0:768]            once, stored bf16
//   G1: [fv_k|fr0] . W1      (M=2B, K=512)  stats pass + min pass
//   T:  [kr_k|kv_k] . W2[:,768:] (M=4B,K=512) stats(+H) pass + final(+H) pass
// conv biases skipped: BN mean-subtraction cancels them exactly.
// ws bracket proven: [69.1, 86.8) MB -> tier2 operative (f32 CVTA staging).

typedef __hip_bfloat16 bf16;
typedef short bf16x8 __attribute__((ext_vector_type(8)));   // 8 bf16 in 4 VGPRs
typedef float f32x4 __attribute__((ext_vector_type(4)));

#define BATCH 32768
#define MODE_STATS 0
#define MODE_MIN1  1
#define MODE_FINAL 2
#define MODE_STORE 3

__device__ __forceinline__ unsigned short f2b(float f) {
    union { float f; unsigned u; } v; v.f = f;
    unsigned r = v.u + 0x7fffu + ((v.u >> 16) & 1u);   // round-to-nearest-even
    return (unsigned short)(r >> 16);
}

__global__ __launch_bounds__(256)
void cvt_kernel(const float* __restrict__ src, unsigned short* __restrict__ dst, int n4)
{
    int i = blockIdx.x * 256 + threadIdx.x;
    if (i >= n4) return;
    float4 v = ((const float4*)src)[i];
    ushort4 h;
    h.x = f2b(v.x); h.y = f2b(v.y); h.z = f2b(v.z); h.w = f2b(v.w);
    ((ushort4*)dst)[i] = h;
}

// out[m,f] = sum_k A[m,k] * W[f, KWOFF+k],  W rows at stride KSTR (bf16).
// A rows gathered from embeddings; row m -> (b=m/RPB, kk=m%RPB); K in 256-wide
// segments. Block tile 128x256, BK=64; 8 waves in 2x4, wave tile 64x64.
// A is double-buffered in LDS (issue-early); B is read straight from L2.
template<int KLEN, int KSTR, int KWOFF, int RPB, int MODE, bool HADD, bool CVTA>
__global__ __launch_bounds__(512, 4)
void gemm_kernel(const int* __restrict__ x, const void* __restrict__ embR_,
                 const void* __restrict__ embV_, const bf16* __restrict__ W,
                 float* __restrict__ accum, const float* __restrict__ coef,
                 bf16* __restrict__ min1, bf16* __restrict__ Hbuf,
                 const float* __restrict__ fcw, float* __restrict__ outacc)
{
    constexpr int KOFF = (RPB == 2) ? 0 : 2;        // window offset in stats
    __shared__ __align__(16) short Ash[2 * 128 * 72];   // dbuf; reused as `red`
    constexpr int NB = 128 / RPB;
    __shared__ int xsh[NB * 12];

    const int tid = threadIdx.x;
    const int lin = blockIdx.x;
    const int m_base = ((lin >> 4) * 8 + (lin & 7)) * 128;
    const int n_base = ((lin >> 3) & 1) * 256;
    const int b0 = m_base / RPB;

    for (int i = tid; i < NB * 12; i += 512) xsh[i] = x[b0 * 12 + i];
    __syncthreads();

    const int lane = tid & 63;
    const int wv   = tid >> 6;                      // 0..7
    const int wmb  = (wv >> 2) * 64;                // wave m-offset (0/64)
    const int wnb  = (wv & 3) * 64;                 // wave n-offset (0/64/128/192)
    const int quad = lane >> 4;
    const int l16  = lane & 15;

    f32x4 acc[4][4];
    #pragma unroll
    for (int i = 0; i < 4; ++i)
        #pragma unroll
        for (int j = 0; j < 4; ++j)
            acc[i][j] = (f32x4){0.f, 0.f, 0.f, 0.f};

    auto pick = [&](int row, int seg, int& idx, int& isRole) {
        if constexpr (RPB == 1) {               // H: hrt = [fv0|fr0|fv1]
            if      (seg == 0) { idx = xsh[row * 12 + 1]; isRole = 0; }
            else if (seg == 1) { idx = xsh[row * 12 + 0]; isRole = 1; }
            else               { idx = xsh[row * 12 + 3]; isRole = 0; }
        } else if constexpr (RPB == 2) {        // GEMM1: [fv_kk | fr0]
            int bl = row >> 1, kk = row & 1;
            if (seg == 0) { idx = xsh[bl * 12 + 2 * kk + 1]; isRole = 0; }
            else          { idx = xsh[bl * 12 + 0];          isRole = 1; }
        } else if constexpr (KLEN == 512) {     // T: [kr_kk | kv_kk]
            int bl = row >> 2, kk = row & 3;
            if (seg == 0) { idx = xsh[bl * 12 + 2 * kk + 4]; isRole = 1; }
            else          { idx = xsh[bl * 12 + 2 * kk + 5]; isRole = 0; }
        } else {                                // tier3 full win2
            int bl = row >> 2, kk = row & 3;
            switch (seg) {
                case 0:  idx = xsh[bl * 12 + 1];          isRole = 0; break;
                case 1:  idx = xsh[bl * 12 + 0];          isRole = 1; break;
                case 2:  idx = xsh[bl * 12 + 3];          isRole = 0; break;
                case 3:  idx = xsh[bl * 12 + 2 * kk + 4]; isRole = 1; break;
                default: idx = xsh[bl * 12 + 2 * kk + 5]; isRole = 0; break;
            }
        }
    };

    // ---- prefetch registers (A only; B is L2-direct) ----
    float4 pf[4];                                   // CVTA path (16 VGPR)
    uint4  pu[2];                                   // bf16 path  (8 VGPR)

    auto issueA = [&](int ch) {
        const int k0  = ch * 64;
        const int seg = k0 >> 8;
        if constexpr (CVTA) {
            const float* embRf = (const float*)embR_;
            const float* embVf = (const float*)embV_;
            const int so4 = (k0 & 255) >> 2;
            #pragma unroll
            for (int i = 0; i < 4; ++i) {
                int flat = tid + i * 512;           // 0..2047
                int row  = flat >> 4;
                int off4 = flat & 15;
                int idx, isRole;
                pick(row, seg, idx, isRole);
                const float* tab = isRole ? embRf : embVf;
                pf[i] = ((const float4*)(tab + (size_t)idx * 256))[so4 + off4];
            }
        } else {
            const bf16* embRb = (const bf16*)embR_;
            const bf16* embVb = (const bf16*)embV_;
            const int so8 = (k0 & 255) >> 3;
            #pragma unroll
            for (int i = 0; i < 2; ++i) {
                int flat = tid + i * 512;           // 0..1023
                int row  = flat >> 3;
                int off8 = flat & 7;
                int idx, isRole;
                pick(row, seg, idx, isRole);
                const bf16* tab = isRole ? embRb : embVb;
                pu[i] = ((const uint4*)(tab + (size_t)idx * 256))[so8 + off8];
            }
        }
    };
    auto writeA = [&](short* As) {
        if constexpr (CVTA) {
            #pragma unroll
            for (int i = 0; i < 4; ++i) {
                int flat = tid + i * 512;
                int row  = flat >> 4;
                int off4 = flat & 15;
                ushort4 h;
                h.x = f2b(pf[i].x); h.y = f2b(pf[i].y);
                h.z = f2b(pf[i].z); h.w = f2b(pf[i].w);
                *(ushort4*)&As[row * 72 + off4 * 4] = h;
            }
        } else {
            #pragma unroll
            for (int i = 0; i < 2; ++i) {
                int flat = tid + i * 512;
                int row  = flat >> 3;
                int off8 = flat & 7;
                *(uint4*)&As[row * 72 + off8 * 8] = pu[i];
            }
        }
    };

    // per-lane B base: row (n_base+wnb+l16), col KWOFF + quad*8
    const bf16* wlane = W + (size_t)(n_base + wnb + l16) * KSTR + KWOFF + quad * 8;

    constexpr int NCH = KLEN / 64;
    issueA(0);
    int buf = 0;
    #pragma unroll 1
    for (int ch = 0; ch < NCH; ++ch) {
        short* As = Ash + buf * (128 * 72);
        writeA(As);                                 // waits on in-flight loads
        if (ch + 1 < NCH) issueA(ch + 1);           // issue-early (in flight)
        __syncthreads();
        const int k0 = ch * 64;
        #pragma unroll
        for (int ks = 0; ks < 64; ks += 32) {
            bf16x8 af[4], bf_[4];
            #pragma unroll
            for (int t = 0; t < 4; ++t)
                af[t]  = *(const bf16x8*)&As[(wmb + t * 16 + l16) * 72 + ks + quad * 8];
            #pragma unroll
            for (int t = 0; t < 4; ++t)
                bf_[t] = *(const bf16x8*)(wlane + (size_t)t * 16 * KSTR + k0 + ks);
            #pragma unroll
            for (int i = 0; i < 4; ++i)
                #pragma unroll
                for (int j = 0; j < 4; ++j)
                    acc[i][j] = __builtin_amdgcn_mfma_f32_16x16x32_bf16(
                        af[i], bf_[j], acc[i][j], 0, 0, 0);
        }
        buf ^= 1;
    }
    __syncthreads();                                // Ash free for reuse below

    // Epilogues. C/D layout: f(col) = l16, m(row) = quad*4 + reg.
    // m = m_base + wmb + i*16 + quad*4 + r;  f = n_base + wnb + j*16 + l16.
    if constexpr (MODE == MODE_STORE) {             // H store (RPB==1)
        #pragma unroll
        for (int j = 0; j < 4; ++j) {
            int f = n_base + wnb + j * 16 + l16;
            #pragma unroll
            for (int i = 0; i < 4; ++i)
                #pragma unroll
                for (int r = 0; r < 4; ++r) {
                    int m = m_base + wmb + i * 16 + quad * 4 + r;
                    *(unsigned short*)&Hbuf[(size_t)m * 512 + f] = f2b(acc[i][j][r]);
                }
        }
    } else if constexpr (MODE == MODE_STATS) {
        float* red = (float*)Ash;                   // Ash dead past last barrier
        for (int i = tid; i < RPB * 512; i += 512) red[i] = 0.f;
        __syncthreads();
        #pragma unroll
        for (int j = 0; j < 4; ++j) {
            int fl = wnb + j * 16 + l16;            // 0..255
            float sr[4] = {0.f,0.f,0.f,0.f}, qr[4] = {0.f,0.f,0.f,0.f};
            #pragma unroll
            for (int i = 0; i < 4; ++i) {
                float h = 0.f;
                if constexpr (HADD) {               // RPB==4: one b per (i,quad)
                    int b = b0 + (wmb >> 2) + i * 4 + quad;
                    h = __bfloat162float(Hbuf[(size_t)b * 512 + n_base + fl]);
                }
                #pragma unroll
                for (int r = 0; r < 4; ++r) {
                    float v = acc[i][j][r] + h;
                    sr[r] += v; qr[r] += v * v;
                }
            }
            #pragma unroll
            for (int r = 0; r < 4; ++r) {
                int kk = r % RPB;
                atomicAdd(&red[kk * 256 + fl], sr[r]);
                atomicAdd(&red[RPB * 256 + kk * 256 + fl], qr[r]);
            }
        }
        __syncthreads();
        for (int idx = tid; idx < RPB * 256; idx += 512) {
            int kw = KOFF + (idx >> 8);
            int f  = n_base + (idx & 255);
            atomicAdd(&accum[kw * 512 + f], red[idx]);
            atomicAdd(&accum[3072 + kw * 512 + f], red[RPB * 256 + idx]);
        }
    } else if constexpr (MODE == MODE_MIN1) {       // RPB==2, windows 0,1
        #pragma unroll
        for (int j = 0; j < 4; ++j) {
            int f = n_base + wnb + j * 16 + l16;
            float a0 = coef[f],        c0 = coef[3072 + f];
            float a1 = coef[512 + f],  c1 = coef[3072 + 512 + f];
            #pragma unroll
            for (int i = 0; i < 4; ++i) {
                #pragma unroll
                for (int rp = 0; rp < 2; ++rp) {
                    int m = m_base + wmb + i * 16 + quad * 4 + rp * 2;
                    float v0 = fmaxf(a0 * acc[i][j][rp * 2]     + c0, 0.f);
                    float v1 = fmaxf(a1 * acc[i][j][rp * 2 + 1] + c1, 0.f);
                    *(unsigned short*)&min1[(size_t)(m >> 1) * 512 + f] =
                        f2b(fminf(v0, v1));
                }
            }
        }
    } else {  // MODE_FINAL: RPB==4, windows 2..5 in r=0..3
        float dotp[4] = {0.f, 0.f, 0.f, 0.f};
        #pragma unroll
        for (int j = 0; j < 4; ++j) {
            int f = n_base + wnb + j * 16 + l16;
            float a[4], c[4];
            #pragma unroll
            for (int r = 0; r < 4; ++r) {
                a[r] = coef[(2 + r) * 512 + f];
                c[r] = coef[3072 + (2 + r) * 512 + f];
            }
            float fw = fcw[f];
            #pragma unroll
            for (int i = 0; i < 4; ++i) {
                int b = b0 + (wmb >> 2) + i * 4 + quad;
                float h = 0.f;
                if constexpr (HADD)
                    h = __bfloat162float(Hbuf[(size_t)b * 512 + f]);
                float mv = 1e30f;
                #pragma unroll
                for (int r = 0; r < 4; ++r)
                    mv = fminf(mv, fmaxf(a[r] * (acc[i][j][r] + h) + c[r], 0.f));
                mv = fminf(mv, __bfloat162float(min1[(size_t)b * 512 + f]));
                dotp[i] += mv * fw;
            }
        }
        #pragma unroll
        for (int i = 0; i < 4; ++i) {
            float v = dotp[i];
            #pragma unroll
            for (int s = 8; s >= 1; s >>= 1) v += __shfl_xor(v, s);
            if (l16 == 0) {
                int b = b0 + (wmb >> 2) + i * 4 + quad;
                atomicAdd(&outacc[b], v);
            }
        }
    }
}

__global__ void bncoef_kernel(const float* __restrict__ accum,
                              const float* __restrict__ g1, const float* __restrict__ be1,
                              const float* __restrict__ g2, const float* __restrict__ be2,
                              float* __restrict__ coef)
{
    int id = blockIdx.x * 256 + threadIdx.x;
    if (id >= 3072) return;
    int kw = id >> 9, f = id & 511;
    float mean = accum[id] * (1.f / BATCH);
    float var  = accum[3072 + id] * (1.f / BATCH) - mean * mean;
    float g  = kw < 2 ? g1[f] : g2[f];
    float be = kw < 2 ? be1[f] : be2[f];
    float a  = g * rsqrtf(var + 1e-5f);
    coef[id] = a;
    coef[3072 + id] = be - a * mean;
}

__global__ void finish_kernel(const float* __restrict__ outacc,
                              const float* __restrict__ fcb, float* __restrict__ out)
{
    int b = blockIdx.x * 256 + threadIdx.x;
    if (b < BATCH)
        out[b] = outacc[b] + fcb[0];
}

extern "C" void kernel_launch(void* const* d_in, const int* in_sizes, int n_in,
                              void* d_out, int out_size, void* d_ws, size_t ws_size,
                              hipStream_t stream)
{
    (void)in_sizes; (void)n_in; (void)out_size;
    const int*   x    = (const int*)  d_in[0];
    const float* embR = (const float*)d_in[2];    // 50000 x 256 f32
    const float* embV = (const float*)d_in[3];    // 50000 x 256 f32
    const float* W1   = (const float*)d_in[4];    // 512 x 2 x 256 f32
    const float* g1   = (const float*)d_in[6];
    const float* be1  = (const float*)d_in[7];
    const float* W2   = (const float*)d_in[8];    // 512 x 5 x 256 f32
    const float* g2   = (const float*)d_in[10];
    const float* be2  = (const float*)d_in[11];
    const float* fcw  = (const float*)d_in[12];   // 512 f32
    const float* fcb  = (const float*)d_in[13];

    char* wsb = (char*)d_ws;
    float* accum  = (float*)wsb;                          //       0: 24 KB
    float* coef   = accum + 6144;                         //   24576: 24 KB
    float* outacc = coef + 6144;                          //   49152: 128 KB
    bf16*  Wbf1   = (bf16*)(wsb + 180224);                //  512 KB
    bf16*  Wbf2   = (bf16*)(wsb + 704512);                // 1.25 MB
    bf16*  Hbuf   = (bf16*)(wsb + 2015232);               // 32 MB (B*512 bf16)
    bf16*  min1   = (bf16*)(wsb + 35569664);              // 32 MB -> 69124096
    bf16*  embRb1 = (bf16*)(wsb + 69124096);              // 24.4 MB (tier1 only)
    bf16*  embVb1 = (bf16*)(wsb + 94724096);              // -> 120324096
    bf16*  min3   = (bf16*)(wsb + 2015232);               // tier3 (H slot)

    const int tier = (ws_size >= 120324096) ? 1
                   : (ws_size >=  69124096) ? 2 : 3;

    hipMemsetAsync(accum, 0, 6144 * sizeof(float), stream);
    hipMemsetAsync(outacc, 0, BATCH * sizeof(float), stream);
    cvt_kernel<<<256, 256, 0, stream>>>(W1, (unsigned short*)Wbf1, 65536);
    cvt_kernel<<<640, 256, 0, stream>>>(W2, (unsigned short*)Wbf2, 163840);

    // Grids: (m_tiles/8 supers) x 2 n-tiles x 8 rows = m_tiles * 2 blocks.
    if (tier == 1) {
        cvt_kernel<<<12500, 256, 0, stream>>>(embR, (unsigned short*)embRb1, 3200000);
        cvt_kernel<<<12500, 256, 0, stream>>>(embV, (unsigned short*)embVb1, 3200000);
        gemm_kernel<768, 1280, 0, 1, MODE_STORE, false, false><<<512, 512, 0, stream>>>(
            x, embRb1, embVb1, Wbf2, nullptr, nullptr, nullptr, Hbuf, nullptr, nullptr);
        gemm_kernel<512, 512, 0, 2, MODE_STATS, false, false><<<1024, 512, 0, stream>>>(
            x, embRb1, embVb1, Wbf1, accum, nullptr, nullptr, nullptr, nullptr, nullptr);
        gemm_kernel<512, 1280, 768, 4, MODE_STATS, true, false><<<2048, 512, 0, stream>>>(
            x, embRb1, embVb1, Wbf2, accum, nullptr, nullptr, Hbuf, nullptr, nullptr);
        bncoef_kernel<<<12, 256, 0, stream>>>(accum, g1, be1, g2, be2, coef);
        gemm_kernel<512, 512, 0, 2, MODE_MIN1, false, false><<<1024, 512, 0, stream>>>(
            x, embRb1, embVb1, Wbf1, nullptr, coef, min1, nullptr, nullptr, nullptr);
        gemm_kernel<512, 1280, 768, 4, MODE_FINAL, true, false><<<2048, 512, 0, stream>>>(
            x, embRb1, embVb1, Wbf2, nullptr, coef, min1, Hbuf, fcw, outacc);
    } else if (tier == 2) {
        gemm_kernel<768, 1280, 0, 1, MODE_STORE, false, true><<<512, 512, 0, stream>>>(
            x, embR, embV, Wbf2, nullptr, nullptr, nullptr, Hbuf, nullptr, nullptr);
        gemm_kernel<512, 512, 0, 2, MODE_STATS, false, true><<<1024, 512, 0, stream>>>(
            x, embR, embV, Wbf1, accum, nullptr, nullptr, nullptr, nullptr, nullptr);
        gemm_kernel<512, 1280, 768, 4, MODE_STATS, true, true><<<2048, 512, 0, stream>>>(
            x, embR, embV, Wbf2, accum, nullptr, nullptr, Hbuf, nullptr, nullptr);
        bncoef_kernel<<<12, 256, 0, stream>>>(accum, g1, be1, g2, be2, coef);
        gemm_kernel<512, 512, 0, 2, MODE_MIN1, false, true><<<1024, 512, 0, stream>>>(
            x, embR, embV, Wbf1, nullptr, coef, min1, nullptr, nullptr, nullptr);
        gemm_kernel<512, 1280, 768, 4, MODE_FINAL, true, true><<<2048, 512, 0, stream>>>(
            x, embR, embV, Wbf2, nullptr, coef, min1, Hbuf, fcw, outacc);
    } else {  // tier3: monolithic K=1280 fallback (35.6 MB)
        gemm_kernel<512, 512, 0, 2, MODE_STATS, false, true><<<1024, 512, 0, stream>>>(
            x, embR, embV, Wbf1, accum, nullptr, nullptr, nullptr, nullptr, nullptr);
        gemm_kernel<1280, 1280, 0, 4, MODE_STATS, false, true><<<2048, 512, 0, stream>>>(
            x, embR, embV, Wbf2, accum, nullptr, nullptr, nullptr, nullptr, nullptr);
        bncoef_kernel<<<12, 256, 0, stream>>>(accum, g1, be1, g2, be2, coef);
        gemm_kernel<512, 512, 0, 2, MODE_MIN1, false, true><<<1024, 512, 0, stream>>>(
            x, embR, embV, Wbf1, nullptr, coef, min3, nullptr, nullptr, nullptr);
        gemm_kernel<1280, 1280, 0, 4, MODE_FINAL, false, true><<<2048, 512, 0, stream>>>(
            x, embR, embV, Wbf2, nullptr, coef, min3, nullptr, fcw, outacc);
    }
    finish_kernel<<<128, 256, 0, stream>>>(outacc, fcb, (float*)d_out);
}